// Round 2
// baseline (326.567 us; speedup 1.0000x reference)
//
#include <hip/hip_runtime.h>
#include <math.h>

#define B_ROWS 131072
#define DDIM 256
#define EPSF 1e-7f
#define NB1 2048   // blocks for k_main
#define NB3 512    // blocks for k_rloss; NB3*256 == B_ROWS

// ---------- ws layout (bytes) ----------
#define WP_OFF   0         // float[8*256]
#define SP_OFF   8192      // float[8*256]
#define Z0_OFF   16384     // float[8*256]
#define SCAL_OFF 24576     // float[32]: [0..7]=b, [8..15]=wdots, [16..23]=a, [24..31]=beta
#define PBSS_OFF 24832     // double[8][NB1]
#define PBPL_OFF 155904    // double[NB1]
#define RV_OFF   172288    // double[8]
#define PL_OFF   172352    // double[1]
#define PBRL_OFF 172416    // double[NB3]
#define HW_OFF   176640    // float[8][B_ROWS]

__device__ __forceinline__ float blockReduce256f(float v, float* sred) {
    int t = threadIdx.x;
    sred[t] = v;
    __syncthreads();
#pragma unroll
    for (int off = 128; off > 0; off >>= 1) {
        if (t < off) sred[t] += sred[t + off];
        __syncthreads();
    }
    float r = sred[0];
    __syncthreads();
    return r;
}

__device__ __forceinline__ double blockReduce256d(double v, double* sred) {
    int t = threadIdx.x;
    sred[t] = v;
    __syncthreads();
#pragma unroll
    for (int off = 128; off > 0; off >>= 1) {
        if (t < off) sred[t] += sred[t + off];
        __syncthreads();
    }
    double r = sred[0];
    __syncthreads();
    return r;
}

// ---------------- k0: parameter corrections + packing ----------------
__global__ __launch_bounds__(256) void k_params(
    const float* __restrict__ pw, const float* __restrict__ pb,
    const float* __restrict__ ps, const float* __restrict__ rz0,
    const float* __restrict__ ra, const float* __restrict__ rb,
    float* __restrict__ wp, float* __restrict__ sp,
    float* __restrict__ z0w, float* __restrict__ scal)
{
    __shared__ float sred[256];
    int d = threadIdx.x;
    for (int p = 0; p < 8; ++p) {
        int i = 2 * p;          // planar layer index (even)
        int ir = i + 1;         // radial layer index (odd)
        float w = pw[i * DDIM + d];
        float s = ps[i * DDIM + d];
        float margin = blockReduce256f(w * s, sred);
        float wn2 = blockReduce256f(w * w, sred);
        float s_corr = s;
        if (margin < -1.0f) {
            float comp = -1.0f + log1pf(expf(margin)) - margin;
            s_corr = s + comp * w / sqrtf(wn2);
        }
        wp[p * DDIM + d] = w;
        sp[p * DDIM + d] = s_corr;
        float wdots = blockReduce256f(w * s_corr, sred);
        z0w[p * DDIM + d] = rz0[ir * DDIM + d];
        if (d == 0) {
            scal[p]      = pb[i];
            scal[8 + p]  = wdots;
            float a = ra[ir];
            float beta = rb[ir];
            if (beta < -a) beta = -a + log1pf(expf(beta));
            scal[16 + p] = a;
            scal[24 + p] = beta;
        }
        __syncthreads();
    }
}

// ---------------- k1: main per-row chain (16 lanes/row, 4 rows/wave) ----------------
__global__ __launch_bounds__(256) void k_main(
    const float* __restrict__ z_in, float* __restrict__ z_out,
    const float* __restrict__ wp, const float* __restrict__ sp,
    const float* __restrict__ z0w, const float* __restrict__ scal,
    float* __restrict__ h_ws, double* __restrict__ pb_ss,
    double* __restrict__ pb_pl)
{
    __shared__ float swp[8 * DDIM];
    __shared__ float ssp[8 * DDIM];
    __shared__ float sz0[8 * DDIM];
    __shared__ double sdred[256];

    for (int idx = threadIdx.x; idx < 8 * DDIM; idx += 256) {
        swp[idx] = wp[idx];
        ssp[idx] = sp[idx];
        sz0[idx] = z0w[idx];
    }
    float pbv[8], wds[8], av[8], bv[8];
#pragma unroll
    for (int p = 0; p < 8; ++p) {
        pbv[p] = scal[p];
        wds[p] = scal[8 + p];
        av[p]  = scal[16 + p];
        bv[p]  = scal[24 + p];
    }
    __syncthreads();

    const int wave = threadIdx.x >> 6;
    const int lane = threadIdx.x & 63;
    const int g = lane >> 4;      // row-in-wave 0..3
    const int j = lane & 15;      // 16-float chunk index within row

    double acc_ss[8];
#pragma unroll
    for (int q = 0; q < 8; ++q) acc_ss[q] = 0.0;
    double acc_pl = 0.0;

    const int ITER = B_ROWS / (NB1 * 16);   // 4
#pragma unroll 1
    for (int it = 0; it < ITER; ++it) {
        // each block covers 64 consecutive rows
        const int row = blockIdx.x * (16 * ITER) + it * 16 + wave * 4 + g;
        const float4* zp = (const float4*)(z_in + (size_t)row * DDIM + j * 16);
        float4 zv[4];
#pragma unroll
        for (int k = 0; k < 4; ++k) zv[k] = zp[k];

#pragma unroll
        for (int i = 0; i < 16; ++i) {
            if ((i & 1) == 0) {               // planar
                const int p = i >> 1;
                const float4* wv4 = (const float4*)(swp + p * DDIM + j * 16);
                float t = 0.0f;
#pragma unroll
                for (int k = 0; k < 4; ++k) {
                    float4 wv = wv4[k];
                    t += zv[k].x * wv.x + zv[k].y * wv.y + zv[k].z * wv.z + zv[k].w * wv.w;
                }
                t += __shfl_xor(t, 1, 64);
                t += __shfl_xor(t, 2, 64);
                t += __shfl_xor(t, 4, 64);
                t += __shfl_xor(t, 8, 64);
                float act = tanhf(t + pbv[p]);
                const float4* sv4 = (const float4*)(ssp + p * DDIM + j * 16);
#pragma unroll
                for (int k = 0; k < 4; ++k) {
                    float4 sv = sv4[k];
                    zv[k].x += sv.x * act; zv[k].y += sv.y * act;
                    zv[k].z += sv.z * act; zv[k].w += sv.w * act;
                }
                float det = 1.0f + (1.0f - act * act) * wds[p];
                float ll = logf(fabsf(det) + EPSF);
                if (j == 0) acc_pl += (double)ll;
            } else {                           // radial
                const int r = i >> 1;
                const float4* z4 = (const float4*)(sz0 + r * DDIM + j * 16);
                float4 rd[4];
                float t = 0.0f;
#pragma unroll
                for (int k = 0; k < 4; ++k) {
                    float4 zz = z4[k];
                    rd[k].x = zv[k].x - zz.x; rd[k].y = zv[k].y - zz.y;
                    rd[k].z = zv[k].z - zz.z; rd[k].w = zv[k].w - zz.w;
                    t += rd[k].x * rd[k].x + rd[k].y * rd[k].y
                       + rd[k].z * rd[k].z + rd[k].w * rd[k].w;
                }
                t += __shfl_xor(t, 1, 64);
                t += __shfl_xor(t, 2, 64);
                t += __shfl_xor(t, 4, 64);
                t += __shfl_xor(t, 8, 64);
                float rr = sqrtf(t);
                float h = 1.0f / (av[r] + rr);
                float bh = bv[r] * h;
#pragma unroll
                for (int k = 0; k < 4; ++k) {
                    zv[k].x += bh * rd[k].x; zv[k].y += bh * rd[k].y;
                    zv[k].z += bh * rd[k].z; zv[k].w += bh * rd[k].w;
                }
                if (j == 0) {
                    h_ws[(size_t)r * B_ROWS + row] = h;
                    acc_ss[r] += (double)t;
                }
            }
        }
        float4* op = (float4*)(z_out + (size_t)row * DDIM + j * 16);
#pragma unroll
        for (int k = 0; k < 4; ++k) op[k] = zv[k];
    }

    // deterministic per-block partials (9 quantities); only j==0 lanes hold data
    __syncthreads();
#pragma unroll 1
    for (int q = 0; q < 9; ++q) {
        double v = (q < 8) ? acc_ss[q] : acc_pl;
        if (j != 0) v = 0.0;
        double t = blockReduce256d(v, sdred);
        if (threadIdx.x == 0) {
            if (q < 8) pb_ss[q * NB1 + blockIdx.x] = t;
            else       pb_pl[blockIdx.x] = t;
        }
    }
}

// ---------------- k2: reduce partials -> R[8], planar loss total ----------------
__global__ __launch_bounds__(256) void k_stats(
    const double* __restrict__ pb_ss, const double* __restrict__ pb_pl,
    double* __restrict__ Rv, double* __restrict__ PL)
{
    __shared__ double sd[256];
    int t = threadIdx.x;
    for (int q = 0; q < 9; ++q) {
        double v = 0.0;
        if (q < 8) { for (int jj = t; jj < NB1; jj += 256) v += pb_ss[q * NB1 + jj]; }
        else       { for (int jj = t; jj < NB1; jj += 256) v += pb_pl[jj]; }
        double tot = blockReduce256d(v, sd);
        if (t == 0) {
            if (q < 8) Rv[q] = sqrt(tot);
            else       PL[0] = tot;
        }
        __syncthreads();
    }
}

// ---------------- k3: radial loss (needs global R) ----------------
__global__ __launch_bounds__(256) void k_rloss(
    const float* __restrict__ h_ws, const float* __restrict__ scal,
    const double* __restrict__ Rv, double* __restrict__ pb_rl)
{
    __shared__ double sd[256];
    __shared__ float sbeta[8], sR[8];
    if (threadIdx.x < 8) {
        sbeta[threadIdx.x] = scal[24 + threadIdx.x];
        sR[threadIdx.x] = (float)Rv[threadIdx.x];
    }
    __syncthreads();
    int row = blockIdx.x * 256 + threadIdx.x;
    double ls = 0.0;
#pragma unroll
    for (int r = 0; r < 8; ++r) {
        float h = h_ws[(size_t)r * B_ROWS + row];
        float beta = sbeta[r];
        float bh = beta * h;
        float t1 = 1.0f + bh;
        float diag = exp2f(255.0f * log2f(t1));        // t1^255, t1>0 guaranteed
        float det = diag * (t1 - beta * h * h * sR[r]);
        ls += (double)logf(fabsf(det) + EPSF);
    }
    double tot = blockReduce256d(ls, sd);
    if (threadIdx.x == 0) pb_rl[blockIdx.x] = tot;
}

// ---------------- k4: final combine ----------------
__global__ __launch_bounds__(256) void k_final(
    const double* __restrict__ pb_rl, const double* __restrict__ PL,
    float* __restrict__ out_loss)
{
    __shared__ double sd[256];
    int t = threadIdx.x;
    double v = 0.0;
    for (int jj = t; jj < NB3; jj += 256) v += pb_rl[jj];
    double tot = blockReduce256d(v, sd);
    if (t == 0) out_loss[0] = (float)((tot + PL[0]) / (double)B_ROWS);
}

extern "C" void kernel_launch(void* const* d_in, const int* in_sizes, int n_in,
                              void* d_out, int out_size, void* d_ws, size_t ws_size,
                              hipStream_t stream) {
    const float* z   = (const float*)d_in[0];
    const float* pw  = (const float*)d_in[1];
    const float* pb  = (const float*)d_in[2];
    const float* ps  = (const float*)d_in[3];
    const float* rz0 = (const float*)d_in[4];
    const float* ra  = (const float*)d_in[5];
    const float* rb  = (const float*)d_in[6];
    float* out = (float*)d_out;

    char* ws = (char*)d_ws;
    float*  wp    = (float*)(ws + WP_OFF);
    float*  sp    = (float*)(ws + SP_OFF);
    float*  z0w   = (float*)(ws + Z0_OFF);
    float*  scal  = (float*)(ws + SCAL_OFF);
    double* pb_ss = (double*)(ws + PBSS_OFF);
    double* pb_pl = (double*)(ws + PBPL_OFF);
    double* Rv    = (double*)(ws + RV_OFF);
    double* PL    = (double*)(ws + PL_OFF);
    double* pb_rl = (double*)(ws + PBRL_OFF);
    float*  h_ws  = (float*)(ws + HW_OFF);

    k_params<<<1, 256, 0, stream>>>(pw, pb, ps, rz0, ra, rb, wp, sp, z0w, scal);
    k_main<<<NB1, 256, 0, stream>>>(z, out, wp, sp, z0w, scal, h_ws, pb_ss, pb_pl);
    k_stats<<<1, 256, 0, stream>>>(pb_ss, pb_pl, Rv, PL);
    k_rloss<<<NB3, 256, 0, stream>>>(h_ws, scal, Rv, pb_rl);
    k_final<<<1, 256, 0, stream>>>(pb_rl, PL, out + (size_t)B_ROWS * DDIM);
}

// Round 3
// 145.572 us; speedup vs baseline: 2.2433x; 2.2433x over previous
//
#include <hip/hip_runtime.h>
#include <math.h>

#define B_ROWS 131072
#define DDIM 256
#define EPSF 1e-7f
#define NB1 8192            // k_main blocks; 16 rows/block
#define NWAVES (NB1 * 4)    // 32768 wave partial slots
#define NB3 512             // k_rloss blocks; NB3*256 == B_ROWS

// ---------- ws layout (bytes) ----------
#define WP_OFF   0          // float[8*256] (permuted)
#define SP_OFF   8192
#define Z0_OFF   16384
#define SCAL_OFF 24576      // float[32]: [0..7]=b, [8..15]=wdots, [16..23]=a, [24..31]=beta
#define PBW_OFF  24704      // float[9][NWAVES] = 1179648 B
#define RV_OFF   1204352    // double[8]
#define PL_OFF   1204416    // double[1]
#define PBRL_OFF 1204424    // double[NB3] = 4096 B
#define HW_OFF   1208576    // _Float16[8][B_ROWS] = 2 MB  (end ~3.31 MB)

__device__ __forceinline__ float blockReduce256f(float v, float* sred) {
    int t = threadIdx.x;
    sred[t] = v;
    __syncthreads();
#pragma unroll
    for (int off = 128; off > 0; off >>= 1) {
        if (t < off) sred[t] += sred[t + off];
        __syncthreads();
    }
    float r = sred[0];
    __syncthreads();
    return r;
}

__device__ __forceinline__ double blockReduce256d(double v, double* sred) {
    int t = threadIdx.x;
    sred[t] = v;
    __syncthreads();
#pragma unroll
    for (int off = 128; off > 0; off >>= 1) {
        if (t < off) sred[t] += sred[t + off];
        __syncthreads();
    }
    double r = sred[0];
    __syncthreads();
    return r;
}

__device__ __forceinline__ float uni(float x) {   // force wave-uniform value into SGPR
    return __int_as_float(__builtin_amdgcn_readfirstlane(__float_as_int(x)));
}

// ---------------- k0: parameter corrections + packing ----------------
__global__ __launch_bounds__(256) void k_params(
    const float* __restrict__ pw, const float* __restrict__ pb,
    const float* __restrict__ ps, const float* __restrict__ rz0,
    const float* __restrict__ ra, const float* __restrict__ rb,
    float* __restrict__ wp, float* __restrict__ sp,
    float* __restrict__ z0w, float* __restrict__ scal)
{
    __shared__ float sred[256];
    int d = threadIdx.x;
    // permuted store index: element d -> k*64 + j*4 + c  (j=d>>4, k=(d>>2)&3, c=d&3)
    int pj = d >> 4, pk = (d >> 2) & 3, pc = d & 3;
    int nd = (pk << 6) | (pj << 2) | pc;
    for (int p = 0; p < 8; ++p) {
        int i = 2 * p;          // planar layer (even)
        int ir = i + 1;         // radial layer (odd)
        float w = pw[i * DDIM + d];
        float s = ps[i * DDIM + d];
        float margin = blockReduce256f(w * s, sred);
        float wn2 = blockReduce256f(w * w, sred);
        float s_corr = s;
        if (margin < -1.0f) {
            float comp = -1.0f + log1pf(expf(margin)) - margin;
            s_corr = s + comp * w / sqrtf(wn2);
        }
        wp[p * DDIM + nd] = w;
        sp[p * DDIM + nd] = s_corr;
        float wdots = blockReduce256f(w * s_corr, sred);
        z0w[p * DDIM + nd] = rz0[ir * DDIM + d];
        if (d == 0) {
            scal[p]      = pb[i];
            scal[8 + p]  = wdots;
            float a = ra[ir];
            float beta = rb[ir];
            if (beta < -a) beta = -a + log1pf(expf(beta));
            scal[16 + p] = a;
            scal[24 + p] = beta;
        }
        __syncthreads();
    }
}

// ---------------- k1: main chain (16 lanes/row, 4 rows/wave, 16 rows/block) ----------------
__global__ __launch_bounds__(256, 4) void k_main(
    const float* __restrict__ z_in, float* __restrict__ z_out,
    const float* __restrict__ wp, const float* __restrict__ sp,
    const float* __restrict__ z0w, const float* __restrict__ scal,
    _Float16* __restrict__ h_ws, float* __restrict__ pbw)
{
    __shared__ float swp[8 * DDIM];
    __shared__ float ssp[8 * DDIM];
    __shared__ float sz0[8 * DDIM];

    for (int idx = threadIdx.x; idx < 8 * DDIM; idx += 256) {
        swp[idx] = wp[idx];     // already permuted by k_params
        ssp[idx] = sp[idx];
        sz0[idx] = z0w[idx];
    }
    float pbv[8], wds[8], av[8], bv[8];
#pragma unroll
    for (int p = 0; p < 8; ++p) {
        pbv[p] = uni(scal[p]);
        wds[p] = uni(scal[8 + p]);
        av[p]  = uni(scal[16 + p]);
        bv[p]  = uni(scal[24 + p]);
    }
    __syncthreads();

    const int wave = threadIdx.x >> 6;
    const int lane = threadIdx.x & 63;
    const int g = lane >> 4;      // row-in-wave 0..3
    const int j = lane & 15;      // chunk index in row
    const int row = blockIdx.x * 16 + wave * 4 + g;

    float4 zv[4];
    {
        const float4* zp = (const float4*)(z_in + (size_t)row * DDIM + j * 16);
#pragma unroll
        for (int k = 0; k < 4; ++k) zv[k] = zp[k];
    }

    float r2s[8];
    float pls = 0.0f;

#pragma unroll
    for (int i = 0; i < 16; ++i) {
        if ((i & 1) == 0) {               // planar
            const int p = i >> 1;
            const float4* wb = ((const float4*)swp) + p * 64 + j;
            float t = 0.0f;
#pragma unroll
            for (int k = 0; k < 4; ++k) {
                float4 wv = wb[k * 16];
                t += zv[k].x * wv.x + zv[k].y * wv.y + zv[k].z * wv.z + zv[k].w * wv.w;
            }
            t += __shfl_xor(t, 1, 64);
            t += __shfl_xor(t, 2, 64);
            t += __shfl_xor(t, 4, 64);
            t += __shfl_xor(t, 8, 64);
            float x = t + pbv[p];
            float e = __expf(2.0f * x);
            float act = 1.0f - 2.0f / (e + 1.0f);       // tanh(x)
            const float4* sb = ((const float4*)ssp) + p * 64 + j;
#pragma unroll
            for (int k = 0; k < 4; ++k) {
                float4 sv = sb[k * 16];
                zv[k].x += sv.x * act; zv[k].y += sv.y * act;
                zv[k].z += sv.z * act; zv[k].w += sv.w * act;
            }
            float det = 1.0f + (1.0f - act * act) * wds[p];
            pls += __logf(fabsf(det) + EPSF);
        } else {                           // radial
            const int r = i >> 1;
            const float4* zb = ((const float4*)sz0) + r * 64 + j;
            float4 rd[4];
            float t = 0.0f;
#pragma unroll
            for (int k = 0; k < 4; ++k) {
                float4 zz = zb[k * 16];
                rd[k].x = zv[k].x - zz.x; rd[k].y = zv[k].y - zz.y;
                rd[k].z = zv[k].z - zz.z; rd[k].w = zv[k].w - zz.w;
                t += rd[k].x * rd[k].x + rd[k].y * rd[k].y
                   + rd[k].z * rd[k].z + rd[k].w * rd[k].w;
            }
            t += __shfl_xor(t, 1, 64);
            t += __shfl_xor(t, 2, 64);
            t += __shfl_xor(t, 4, 64);
            t += __shfl_xor(t, 8, 64);
            float rr = sqrtf(t);
            float h = 1.0f / (av[r] + rr);
            float bh = bv[r] * h;
#pragma unroll
            for (int k = 0; k < 4; ++k) {
                zv[k].x += bh * rd[k].x; zv[k].y += bh * rd[k].y;
                zv[k].z += bh * rd[k].z; zv[k].w += bh * rd[k].w;
            }
            r2s[r] = t;
            if (j == 0) h_ws[(size_t)r * B_ROWS + row] = (_Float16)h;
        }
    }

    {
        float4* op = (float4*)(z_out + (size_t)row * DDIM + j * 16);
#pragma unroll
        for (int k = 0; k < 4; ++k) op[k] = zv[k];
    }

    // per-wave partials: mask to one lane per row, butterfly across the 4 rows
    const int waveId = blockIdx.x * 4 + wave;
#pragma unroll
    for (int q = 0; q < 9; ++q) {
        float v = (q < 8) ? r2s[q] : pls;
        if (j != 0) v = 0.0f;
        v += __shfl_xor(v, 16, 64);
        v += __shfl_xor(v, 32, 64);
        if (lane == 0) pbw[q * NWAVES + waveId] = v;
    }
}

// ---------------- k2: reduce wave partials -> R[8], planar loss (9 blocks) ----------------
__global__ __launch_bounds__(256) void k_stats(
    const float* __restrict__ pbw, double* __restrict__ Rv, double* __restrict__ PL)
{
    __shared__ double sd[256];
    const int q = blockIdx.x;
    const int t = threadIdx.x;
    double v = 0.0;
    for (int i = t; i < NWAVES; i += 256) v += (double)pbw[q * NWAVES + i];
    double tot = blockReduce256d(v, sd);
    if (t == 0) {
        if (q < 8) Rv[q] = sqrt(tot);
        else       PL[0] = tot;
    }
}

// ---------------- k3: radial loss (needs global R) ----------------
__global__ __launch_bounds__(256) void k_rloss(
    const _Float16* __restrict__ h_ws, const float* __restrict__ scal,
    const double* __restrict__ Rv, double* __restrict__ pb_rl)
{
    __shared__ double sd[256];
    __shared__ float sbeta[8], sR[8];
    if (threadIdx.x < 8) {
        sbeta[threadIdx.x] = scal[24 + threadIdx.x];
        sR[threadIdx.x] = (float)Rv[threadIdx.x];
    }
    __syncthreads();
    int row = blockIdx.x * 256 + threadIdx.x;
    double ls = 0.0;
#pragma unroll
    for (int r = 0; r < 8; ++r) {
        float h = (float)h_ws[(size_t)r * B_ROWS + row];
        float beta = sbeta[r];
        float bh = beta * h;
        float t1 = 1.0f + bh;
        float diag = exp2f(255.0f * __log2f(t1));      // t1^255, t1>0 guaranteed
        float det = diag * (t1 - beta * h * h * sR[r]);
        ls += (double)__logf(fabsf(det) + EPSF);
    }
    double tot = blockReduce256d(ls, sd);
    if (threadIdx.x == 0) pb_rl[blockIdx.x] = tot;
}

// ---------------- k4: final combine ----------------
__global__ __launch_bounds__(256) void k_final(
    const double* __restrict__ pb_rl, const double* __restrict__ PL,
    float* __restrict__ out_loss)
{
    __shared__ double sd[256];
    int t = threadIdx.x;
    double v = 0.0;
    for (int jj = t; jj < NB3; jj += 256) v += pb_rl[jj];
    double tot = blockReduce256d(v, sd);
    if (t == 0) out_loss[0] = (float)((tot + PL[0]) / (double)B_ROWS);
}

extern "C" void kernel_launch(void* const* d_in, const int* in_sizes, int n_in,
                              void* d_out, int out_size, void* d_ws, size_t ws_size,
                              hipStream_t stream) {
    const float* z   = (const float*)d_in[0];
    const float* pw  = (const float*)d_in[1];
    const float* pb  = (const float*)d_in[2];
    const float* ps  = (const float*)d_in[3];
    const float* rz0 = (const float*)d_in[4];
    const float* ra  = (const float*)d_in[5];
    const float* rb  = (const float*)d_in[6];
    float* out = (float*)d_out;

    char* ws = (char*)d_ws;
    float*    wp    = (float*)(ws + WP_OFF);
    float*    sp    = (float*)(ws + SP_OFF);
    float*    z0w   = (float*)(ws + Z0_OFF);
    float*    scal  = (float*)(ws + SCAL_OFF);
    float*    pbw   = (float*)(ws + PBW_OFF);
    double*   Rv    = (double*)(ws + RV_OFF);
    double*   PL    = (double*)(ws + PL_OFF);
    double*   pb_rl = (double*)(ws + PBRL_OFF);
    _Float16* h_ws  = (_Float16*)(ws + HW_OFF);

    k_params<<<1, 256, 0, stream>>>(pw, pb, ps, rz0, ra, rb, wp, sp, z0w, scal);
    k_main<<<NB1, 256, 0, stream>>>(z, out, wp, sp, z0w, scal, h_ws, pbw);
    k_stats<<<9, 256, 0, stream>>>(pbw, Rv, PL);
    k_rloss<<<NB3, 256, 0, stream>>>(h_ws, scal, Rv, pb_rl);
    k_final<<<1, 256, 0, stream>>>(pb_rl, PL, out + (size_t)B_ROWS * DDIM);
}

// Round 4
// 127.946 us; speedup vs baseline: 2.5524x; 1.1378x over previous
//
#include <hip/hip_runtime.h>
#include <hip/hip_fp16.h>
#include <math.h>

#define B_ROWS 131072
#define DDIM 256
#define EPSF 1e-7f
#define NB1 4096            // k_main blocks; 512 thr, 8 waves, 32 rows/block
#define NWAVES (NB1 * 8)    // 32768 per-wave partial slots
#define NB3 512             // k_rloss blocks; NB3*256 == B_ROWS

// ---------- ws layout (bytes) ----------
#define PBW_OFF  0          // float[9][NWAVES] = 1179648
#define RV_OFF   1179648    // double[8]
#define PL_OFF   1179712    // double[1]
#define PBRL_OFF 1179776    // double[NB3] = 4096
#define HW_OFF   1183872    // __half[B_ROWS][8] = 2 MB (end ~3.28 MB)

__device__ __forceinline__ float uni(float x) {   // wave-uniform -> SGPR
    return __int_as_float(__builtin_amdgcn_readfirstlane(__float_as_int(x)));
}

// ---------------- k1: fused params + main chain ----------------
// 512 threads = 8 waves; wave handles 4 rows (16 lanes/row, 16 elems/lane).
__global__ __launch_bounds__(512, 8) void k_main(
    const float* __restrict__ z_in, float* __restrict__ z_out,
    const float* __restrict__ pw, const float* __restrict__ pb,
    const float* __restrict__ ps, const float* __restrict__ rz0,
    const float* __restrict__ ra, const float* __restrict__ rb,
    __half* __restrict__ h_ws, float* __restrict__ pbw)
{
    __shared__ float swp[8 * DDIM];
    __shared__ float ssp[8 * DDIM];
    __shared__ float sz0[8 * DDIM];
    __shared__ float sscal[32];   // [0..7]=b, [8..15]=wdots, [16..23]=a, [24..31]=beta

    const int wave = threadIdx.x >> 6;
    const int lane = threadIdx.x & 63;

    // --- prologue: wave p computes layer-pair p's corrected params (sync-free) ---
    {
        const int p = wave;
        const int ip = 2 * p, ir = 2 * p + 1;
        float4 wv  = ((const float4*)(pw  + ip * DDIM))[lane];
        float4 sv  = ((const float4*)(ps  + ip * DDIM))[lane];
        float4 z0v = ((const float4*)(rz0 + ir * DDIM))[lane];
        float m  = wv.x * sv.x + wv.y * sv.y + wv.z * sv.z + wv.w * sv.w;
        float n2 = wv.x * wv.x + wv.y * wv.y + wv.z * wv.z + wv.w * wv.w;
#pragma unroll
        for (int o = 1; o < 64; o <<= 1) {
            m  += __shfl_xor(m,  o, 64);
            n2 += __shfl_xor(n2, o, 64);
        }
        if (m < -1.0f) {                      // wave-uniform branch
            float comp = -1.0f + log1pf(expf(m)) - m;
            float f = comp / sqrtf(n2);
            sv.x += f * wv.x; sv.y += f * wv.y; sv.z += f * wv.z; sv.w += f * wv.w;
        }
        float wd = wv.x * sv.x + wv.y * sv.y + wv.z * sv.z + wv.w * sv.w;
#pragma unroll
        for (int o = 1; o < 64; o <<= 1) wd += __shfl_xor(wd, o, 64);
        // permuted store: element d=lane*4+c -> ((lane&3)<<6)|((lane>>2)<<2)|c
        const int nd = ((lane & 3) << 6) | ((lane >> 2) << 2);
        *((float4*)(swp + p * DDIM + nd)) = wv;
        *((float4*)(ssp + p * DDIM + nd)) = sv;
        *((float4*)(sz0 + p * DDIM + nd)) = z0v;
        if (lane == 0) {
            sscal[p]      = pb[ip];
            sscal[8 + p]  = wd;
            float a = ra[ir], bt = rb[ir];
            if (bt < -a) bt = -a + log1pf(expf(bt));
            sscal[16 + p] = a;
            sscal[24 + p] = bt;
        }
    }
    __syncthreads();

    float pbv[8], wds[8], av[8], bv[8];
#pragma unroll
    for (int p = 0; p < 8; ++p) {
        pbv[p] = uni(sscal[p]);
        wds[p] = uni(sscal[8 + p]);
        av[p]  = uni(sscal[16 + p]);
        bv[p]  = uni(sscal[24 + p]);
    }

    const int g = lane >> 4;      // row-in-wave 0..3
    const int j = lane & 15;      // chunk index in row
    const int row = blockIdx.x * 32 + wave * 4 + g;

    float4 zv[4];
    {
        const float4* zp = (const float4*)(z_in + (size_t)row * DDIM + j * 16);
#pragma unroll
        for (int k = 0; k < 4; ++k) zv[k] = zp[k];
    }

    float r2s[8];
    float pls = 0.0f;
    unsigned hw32[4];

#pragma unroll
    for (int i = 0; i < 16; ++i) {
        if ((i & 1) == 0) {               // planar
            const int p = i >> 1;
            const float4* wb = ((const float4*)swp) + p * 64 + j;
            float t = 0.0f;
#pragma unroll
            for (int k = 0; k < 4; ++k) {
                float4 wv = wb[k * 16];
                t += zv[k].x * wv.x + zv[k].y * wv.y + zv[k].z * wv.z + zv[k].w * wv.w;
            }
            t += __shfl_xor(t, 1, 64);
            t += __shfl_xor(t, 2, 64);
            t += __shfl_xor(t, 4, 64);
            t += __shfl_xor(t, 8, 64);
            float x = t + pbv[p];
            float e = __expf(2.0f * x);
            float act = 1.0f - 2.0f / (e + 1.0f);       // tanh(x)
            const float4* sb = ((const float4*)ssp) + p * 64 + j;
#pragma unroll
            for (int k = 0; k < 4; ++k) {
                float4 sv = sb[k * 16];
                zv[k].x += sv.x * act; zv[k].y += sv.y * act;
                zv[k].z += sv.z * act; zv[k].w += sv.w * act;
            }
            float det = 1.0f + (1.0f - act * act) * wds[p];
            pls += __logf(fabsf(det) + EPSF);
        } else {                           // radial
            const int r = i >> 1;
            const float4* zb = ((const float4*)sz0) + r * 64 + j;
            float4 rd[4];
            float t = 0.0f;
#pragma unroll
            for (int k = 0; k < 4; ++k) {
                float4 zz = zb[k * 16];
                rd[k].x = zv[k].x - zz.x; rd[k].y = zv[k].y - zz.y;
                rd[k].z = zv[k].z - zz.z; rd[k].w = zv[k].w - zz.w;
                t += rd[k].x * rd[k].x + rd[k].y * rd[k].y
                   + rd[k].z * rd[k].z + rd[k].w * rd[k].w;
            }
            t += __shfl_xor(t, 1, 64);
            t += __shfl_xor(t, 2, 64);
            t += __shfl_xor(t, 4, 64);
            t += __shfl_xor(t, 8, 64);
            float rr = sqrtf(t);
            float h = 1.0f / (av[r] + rr);
            float bh = bv[r] * h;
#pragma unroll
            for (int k = 0; k < 4; ++k) {
                zv[k].x += bh * rd[k].x; zv[k].y += bh * rd[k].y;
                zv[k].z += bh * rd[k].z; zv[k].w += bh * rd[k].w;
            }
            r2s[r] = t;
            unsigned hu = (unsigned)__half_as_ushort(__float2half(h));
            if ((r & 1) == 0) hw32[r >> 1] = hu;
            else              hw32[r >> 1] |= hu << 16;
        }
    }

    {
        float4* op = (float4*)(z_out + (size_t)row * DDIM + j * 16);
#pragma unroll
        for (int k = 0; k < 4; ++k) op[k] = zv[k];
        if (j == 0)
            ((uint4*)h_ws)[row] = make_uint4(hw32[0], hw32[1], hw32[2], hw32[3]);
    }

    // per-wave partials
    const int waveId = blockIdx.x * 8 + wave;
#pragma unroll
    for (int q = 0; q < 9; ++q) {
        float v = (q < 8) ? r2s[q] : pls;
        if (j != 0) v = 0.0f;
        v += __shfl_xor(v, 16, 64);
        v += __shfl_xor(v, 32, 64);
        if (lane == 0) pbw[q * NWAVES + waveId] = v;
    }
}

// ---------------- k2: reduce wave partials -> R[8], planar loss (9 blocks) ----------------
__global__ __launch_bounds__(1024) void k_stats(
    const float* __restrict__ pbw, double* __restrict__ Rv, double* __restrict__ PL)
{
    __shared__ double sd[1024];
    const int q = blockIdx.x;
    const int t = threadIdx.x;
    double v = 0.0;
    for (int i = t; i < NWAVES; i += 1024) v += (double)pbw[q * NWAVES + i];
    sd[t] = v;
    __syncthreads();
#pragma unroll
    for (int off = 512; off > 0; off >>= 1) {
        if (t < off) sd[t] += sd[t + off];
        __syncthreads();
    }
    if (t == 0) {
        if (q < 8) Rv[q] = sqrt(sd[0]);
        else       PL[0] = sd[0];
    }
}

// ---------------- k3: radial loss (needs global R) ----------------
__global__ __launch_bounds__(256) void k_rloss(
    const __half* __restrict__ h_ws, const float* __restrict__ ra,
    const float* __restrict__ rb, const double* __restrict__ Rv,
    double* __restrict__ pb_rl)
{
    __shared__ double sd[256];
    __shared__ float sbeta[8], sR[8];
    if (threadIdx.x < 8) {
        int r = threadIdx.x;
        float a = ra[2 * r + 1], bt = rb[2 * r + 1];
        if (bt < -a) bt = -a + log1pf(expf(bt));
        sbeta[r] = bt;
        sR[r] = (float)Rv[r];
    }
    __syncthreads();
    const int row = blockIdx.x * 256 + threadIdx.x;
    uint4 hp = ((const uint4*)h_ws)[row];
    unsigned hw[4] = {hp.x, hp.y, hp.z, hp.w};
    double ls = 0.0;
#pragma unroll
    for (int r = 0; r < 8; ++r) {
        unsigned hu = (hw[r >> 1] >> ((r & 1) * 16)) & 0xFFFFu;
        float h = __half2float(__ushort_as_half((unsigned short)hu));
        float beta = sbeta[r];
        float bh = beta * h;
        float t1 = 1.0f + bh;
        float diag = exp2f(255.0f * __log2f(t1));      // t1^255, t1>0
        float det = diag * (t1 - beta * h * h * sR[r]);
        ls += (double)__logf(fabsf(det) + EPSF);
    }
    sd[threadIdx.x] = ls;
    __syncthreads();
#pragma unroll
    for (int off = 128; off > 0; off >>= 1) {
        if (threadIdx.x < off) sd[threadIdx.x] += sd[threadIdx.x + off];
        __syncthreads();
    }
    if (threadIdx.x == 0) pb_rl[blockIdx.x] = sd[0];
}

// ---------------- k4: final combine ----------------
__global__ __launch_bounds__(256) void k_final(
    const double* __restrict__ pb_rl, const double* __restrict__ PL,
    float* __restrict__ out_loss)
{
    __shared__ double sd[256];
    int t = threadIdx.x;
    double v = 0.0;
    for (int jj = t; jj < NB3; jj += 256) v += pb_rl[jj];
    sd[t] = v;
    __syncthreads();
#pragma unroll
    for (int off = 128; off > 0; off >>= 1) {
        if (t < off) sd[t] += sd[t + off];
        __syncthreads();
    }
    if (t == 0) out_loss[0] = (float)((sd[0] + PL[0]) / (double)B_ROWS);
}

extern "C" void kernel_launch(void* const* d_in, const int* in_sizes, int n_in,
                              void* d_out, int out_size, void* d_ws, size_t ws_size,
                              hipStream_t stream) {
    const float* z   = (const float*)d_in[0];
    const float* pw  = (const float*)d_in[1];
    const float* pb  = (const float*)d_in[2];
    const float* ps  = (const float*)d_in[3];
    const float* rz0 = (const float*)d_in[4];
    const float* ra  = (const float*)d_in[5];
    const float* rb  = (const float*)d_in[6];
    float* out = (float*)d_out;

    char* ws = (char*)d_ws;
    float*  pbw   = (float*)(ws + PBW_OFF);
    double* Rv    = (double*)(ws + RV_OFF);
    double* PL    = (double*)(ws + PL_OFF);
    double* pb_rl = (double*)(ws + PBRL_OFF);
    __half* h_ws  = (__half*)(ws + HW_OFF);

    k_main<<<NB1, 512, 0, stream>>>(z, out, pw, pb, ps, rz0, ra, rb, h_ws, pbw);
    k_stats<<<9, 1024, 0, stream>>>(pbw, Rv, PL);
    k_rloss<<<NB3, 256, 0, stream>>>(h_ws, ra, rb, Rv, pb_rl);
    k_final<<<1, 256, 0, stream>>>(pb_rl, PL, out + (size_t)B_ROWS * DDIM);
}

// Round 5
// 106.399 us; speedup vs baseline: 3.0693x; 1.2025x over previous
//
#include <hip/hip_runtime.h>
#include <hip/hip_fp16.h>
#include <math.h>

#define B_ROWS 131072
#define DDIM 256
#define EPSF 1e-7f
#define NB1 4096            // k_main blocks; 512 thr, 8 waves, 32 rows/block
#define NWAVES (NB1 * 8)    // 32768 per-wave partial slots
#define NB3 512             // k_rloss blocks; NB3*256 == B_ROWS

// ---------- ws layout (bytes) ----------
#define PBW_OFF  0          // float[NWAVES][9] = 1179648
#define RV_OFF   1179648    // double[8]
#define PL_OFF   1179712    // double[1]
#define PBRL_OFF 1179776    // double[NB3] = 4096
#define HW_OFF   1183872    // __half[B_ROWS][8] = 2 MB (end ~3.28 MB)

__device__ __forceinline__ float uni(float x) {   // wave-uniform -> SGPR
    return __int_as_float(__builtin_amdgcn_readfirstlane(__float_as_int(x)));
}

// ---------------- k1: fused params + main chain ----------------
// 512 threads = 8 waves; wave handles 4 rows (16 lanes/row, 16 elems/lane).
// __launch_bounds__(512,6): 24 waves/CU, VGPR cap ~85 -> no spills (R4's (512,8)
// forced 32 VGPRs and spilled ~170MB of scratch traffic).
__global__ __launch_bounds__(512, 6) void k_main(
    const float* __restrict__ z_in, float* __restrict__ z_out,
    const float* __restrict__ pw, const float* __restrict__ pb,
    const float* __restrict__ ps, const float* __restrict__ rz0,
    const float* __restrict__ ra, const float* __restrict__ rb,
    __half* __restrict__ h_ws, float* __restrict__ pbw)
{
    __shared__ float swp[8 * DDIM];
    __shared__ float ssp[8 * DDIM];
    __shared__ float sz0[8 * DDIM];
    __shared__ float sscal[32];   // [0..7]=b, [8..15]=wdots, [16..23]=a, [24..31]=beta

    const int wave = threadIdx.x >> 6;
    const int lane = threadIdx.x & 63;

    // --- prologue: wave p computes layer-pair p's corrected params (sync-free) ---
    {
        const int p = wave;
        const int ip = 2 * p, ir = 2 * p + 1;
        float4 wv  = ((const float4*)(pw  + ip * DDIM))[lane];
        float4 sv  = ((const float4*)(ps  + ip * DDIM))[lane];
        float4 z0v = ((const float4*)(rz0 + ir * DDIM))[lane];
        float m  = wv.x * sv.x + wv.y * sv.y + wv.z * sv.z + wv.w * sv.w;
        float n2 = wv.x * wv.x + wv.y * wv.y + wv.z * wv.z + wv.w * wv.w;
#pragma unroll
        for (int o = 1; o < 64; o <<= 1) {
            m  += __shfl_xor(m,  o, 64);
            n2 += __shfl_xor(n2, o, 64);
        }
        if (m < -1.0f) {                      // wave-uniform branch
            float comp = -1.0f + log1pf(expf(m)) - m;
            float f = comp / sqrtf(n2);
            sv.x += f * wv.x; sv.y += f * wv.y; sv.z += f * wv.z; sv.w += f * wv.w;
        }
        float wd = wv.x * sv.x + wv.y * sv.y + wv.z * sv.z + wv.w * sv.w;
#pragma unroll
        for (int o = 1; o < 64; o <<= 1) wd += __shfl_xor(wd, o, 64);
        // permuted store: element d=lane*4+c -> ((lane&3)<<6)|((lane>>2)<<2)|c
        const int nd = ((lane & 3) << 6) | ((lane >> 2) << 2);
        *((float4*)(swp + p * DDIM + nd)) = wv;
        *((float4*)(ssp + p * DDIM + nd)) = sv;
        *((float4*)(sz0 + p * DDIM + nd)) = z0v;
        if (lane == 0) {
            sscal[p]      = pb[ip];
            sscal[8 + p]  = wd;
            float a = ra[ir], bt = rb[ir];
            if (bt < -a) bt = -a + log1pf(expf(bt));
            sscal[16 + p] = a;
            sscal[24 + p] = bt;
        }
    }
    __syncthreads();

    float pbv[8], wds[8], av[8], bv[8];
#pragma unroll
    for (int p = 0; p < 8; ++p) {
        pbv[p] = uni(sscal[p]);
        wds[p] = uni(sscal[8 + p]);
        av[p]  = uni(sscal[16 + p]);
        bv[p]  = uni(sscal[24 + p]);
    }

    const int g = lane >> 4;      // row-in-wave 0..3
    const int j = lane & 15;      // chunk index in row
    const int row = blockIdx.x * 32 + wave * 4 + g;

    float4 zv[4];
    {
        const float4* zp = (const float4*)(z_in + (size_t)row * DDIM + j * 16);
#pragma unroll
        for (int k = 0; k < 4; ++k) zv[k] = zp[k];
    }

    float r2s[8];
    float pls = 0.0f;
    unsigned hw32[4];

#pragma unroll
    for (int i = 0; i < 16; ++i) {
        if ((i & 1) == 0) {               // planar
            const int p = i >> 1;
            const float4* wb = ((const float4*)swp) + p * 64 + j;
            float t = 0.0f;
#pragma unroll
            for (int k = 0; k < 4; ++k) {
                float4 wv = wb[k * 16];
                t += zv[k].x * wv.x + zv[k].y * wv.y + zv[k].z * wv.z + zv[k].w * wv.w;
            }
            t += __shfl_xor(t, 1, 64);
            t += __shfl_xor(t, 2, 64);
            t += __shfl_xor(t, 4, 64);
            t += __shfl_xor(t, 8, 64);
            float x = t + pbv[p];
            float e = __expf(2.0f * x);
            float act = 1.0f - 2.0f / (e + 1.0f);       // tanh(x)
            const float4* sb = ((const float4*)ssp) + p * 64 + j;
#pragma unroll
            for (int k = 0; k < 4; ++k) {
                float4 sv = sb[k * 16];
                zv[k].x += sv.x * act; zv[k].y += sv.y * act;
                zv[k].z += sv.z * act; zv[k].w += sv.w * act;
            }
            float det = 1.0f + (1.0f - act * act) * wds[p];
            pls += __logf(fabsf(det) + EPSF);
        } else {                           // radial
            const int r = i >> 1;
            const float4* zb = ((const float4*)sz0) + r * 64 + j;
            float4 rd[4];
            float t = 0.0f;
#pragma unroll
            for (int k = 0; k < 4; ++k) {
                float4 zz = zb[k * 16];
                rd[k].x = zv[k].x - zz.x; rd[k].y = zv[k].y - zz.y;
                rd[k].z = zv[k].z - zz.z; rd[k].w = zv[k].w - zz.w;
                t += rd[k].x * rd[k].x + rd[k].y * rd[k].y
                   + rd[k].z * rd[k].z + rd[k].w * rd[k].w;
            }
            t += __shfl_xor(t, 1, 64);
            t += __shfl_xor(t, 2, 64);
            t += __shfl_xor(t, 4, 64);
            t += __shfl_xor(t, 8, 64);
            float rr = sqrtf(t);
            float h = 1.0f / (av[r] + rr);
            float bh = bv[r] * h;
#pragma unroll
            for (int k = 0; k < 4; ++k) {
                zv[k].x += bh * rd[k].x; zv[k].y += bh * rd[k].y;
                zv[k].z += bh * rd[k].z; zv[k].w += bh * rd[k].w;
            }
            r2s[r] = t;
            unsigned hu = (unsigned)__half_as_ushort(__float2half(h));
            if ((r & 1) == 0) hw32[r >> 1] = hu;
            else              hw32[r >> 1] |= hu << 16;
        }
    }

    {
        float4* op = (float4*)(z_out + (size_t)row * DDIM + j * 16);
#pragma unroll
        for (int k = 0; k < 4; ++k) op[k] = zv[k];
        if (j == 0)
            ((uint4*)h_ws)[row] = make_uint4(hw32[0], hw32[1], hw32[2], hw32[3]);
    }

    // per-wave partials: full butterfly then lane 0 stores 9 contiguous floats
    const int waveId = blockIdx.x * 8 + wave;
#pragma unroll
    for (int q = 0; q < 9; ++q) {
        float v = (q < 8) ? r2s[q] : pls;
        if (j != 0) v = 0.0f;
        v += __shfl_xor(v, 16, 64);
        v += __shfl_xor(v, 32, 64);
        if (lane == 0) pbw[waveId * 9 + q] = v;
    }
}

// ---------------- k2: reduce wave partials -> R[8], planar loss (9 blocks) ----------------
__global__ __launch_bounds__(1024) void k_stats(
    const float* __restrict__ pbw, double* __restrict__ Rv, double* __restrict__ PL)
{
    __shared__ double sd[1024];
    const int q = blockIdx.x;
    const int t = threadIdx.x;
    double v = 0.0;
    for (int i = t; i < NWAVES; i += 1024) v += (double)pbw[i * 9 + q];
    sd[t] = v;
    __syncthreads();
#pragma unroll
    for (int off = 512; off > 0; off >>= 1) {
        if (t < off) sd[t] += sd[t + off];
        __syncthreads();
    }
    if (t == 0) {
        if (q < 8) Rv[q] = sqrt(sd[0]);
        else       PL[0] = sd[0];
    }
}

// ---------------- k3: radial loss (needs global R) ----------------
__global__ __launch_bounds__(256) void k_rloss(
    const __half* __restrict__ h_ws, const float* __restrict__ ra,
    const float* __restrict__ rb, const double* __restrict__ Rv,
    double* __restrict__ pb_rl)
{
    __shared__ double sd[256];
    __shared__ float sbeta[8], sR[8];
    if (threadIdx.x < 8) {
        int r = threadIdx.x;
        float a = ra[2 * r + 1], bt = rb[2 * r + 1];
        if (bt < -a) bt = -a + log1pf(expf(bt));
        sbeta[r] = bt;
        sR[r] = (float)Rv[r];
    }
    __syncthreads();
    const int row = blockIdx.x * 256 + threadIdx.x;
    uint4 hp = ((const uint4*)h_ws)[row];
    unsigned hw[4] = {hp.x, hp.y, hp.z, hp.w};
    double ls = 0.0;
#pragma unroll
    for (int r = 0; r < 8; ++r) {
        unsigned hu = (hw[r >> 1] >> ((r & 1) * 16)) & 0xFFFFu;
        float h = __half2float(__ushort_as_half((unsigned short)hu));
        float beta = sbeta[r];
        float bh = beta * h;
        float t1 = 1.0f + bh;
        float diag = exp2f(255.0f * __log2f(t1));      // t1^255, t1>0
        float det = diag * (t1 - beta * h * h * sR[r]);
        ls += (double)__logf(fabsf(det) + EPSF);
    }
    sd[threadIdx.x] = ls;
    __syncthreads();
#pragma unroll
    for (int off = 128; off > 0; off >>= 1) {
        if (threadIdx.x < off) sd[threadIdx.x] += sd[threadIdx.x + off];
        __syncthreads();
    }
    if (threadIdx.x == 0) pb_rl[blockIdx.x] = sd[0];
}

// ---------------- k4: final combine ----------------
__global__ __launch_bounds__(256) void k_final(
    const double* __restrict__ pb_rl, const double* __restrict__ PL,
    float* __restrict__ out_loss)
{
    __shared__ double sd[256];
    int t = threadIdx.x;
    double v = 0.0;
    for (int jj = t; jj < NB3; jj += 256) v += pb_rl[jj];
    sd[t] = v;
    __syncthreads();
#pragma unroll
    for (int off = 128; off > 0; off >>= 1) {
        if (t < off) sd[t] += sd[t + off];
        __syncthreads();
    }
    if (t == 0) out_loss[0] = (float)((sd[0] + PL[0]) / (double)B_ROWS);
}

extern "C" void kernel_launch(void* const* d_in, const int* in_sizes, int n_in,
                              void* d_out, int out_size, void* d_ws, size_t ws_size,
                              hipStream_t stream) {
    const float* z   = (const float*)d_in[0];
    const float* pw  = (const float*)d_in[1];
    const float* pb  = (const float*)d_in[2];
    const float* ps  = (const float*)d_in[3];
    const float* rz0 = (const float*)d_in[4];
    const float* ra  = (const float*)d_in[5];
    const float* rb  = (const float*)d_in[6];
    float* out = (float*)d_out;

    char* ws = (char*)d_ws;
    float*  pbw   = (float*)(ws + PBW_OFF);
    double* Rv    = (double*)(ws + RV_OFF);
    double* PL    = (double*)(ws + PL_OFF);
    double* pb_rl = (double*)(ws + PBRL_OFF);
    __half* h_ws  = (__half*)(ws + HW_OFF);

    k_main<<<NB1, 512, 0, stream>>>(z, out, pw, pb, ps, rz0, ra, rb, h_ws, pbw);
    k_stats<<<9, 1024, 0, stream>>>(pbw, Rv, PL);
    k_rloss<<<NB3, 256, 0, stream>>>(h_ws, ra, rb, Rv, pb_rl);
    k_final<<<1, 256, 0, stream>>>(pb_rl, PL, out + (size_t)B_ROWS * DDIM);
}

// Round 6
// 98.320 us; speedup vs baseline: 3.3215x; 1.0822x over previous
//
#include <hip/hip_runtime.h>
#include <hip/hip_fp16.h>
#include <math.h>

#define B_ROWS 131072
#define DDIM 256
#define EPSF 1e-7f
#define NB1 4096            // k_main blocks; 512 thr, 8 waves, 32 rows/block
#define NWAVES (NB1 * 8)    // 32768 per-wave partial slots
#define NB3 512             // k_rloss blocks; NB3*256 == B_ROWS

// ---------- ws layout (bytes) ----------
#define PBW_OFF  0          // float[NWAVES][9] = 1179648
#define RV_OFF   1179648    // double[8]
#define PL_OFF   1179712    // double[1]
#define PBRL_OFF 1179776    // double[NB3] = 4096
#define HW_OFF   1183872    // __half[B_ROWS][8] = 2 MB (end ~3.28 MB)

__device__ __forceinline__ float uni(float x) {   // wave-uniform -> SGPR
    return __int_as_float(__builtin_amdgcn_readfirstlane(__float_as_int(x)));
}

// DPP-based add: v += v permuted by ctrl (within 16-lane DPP rows). VALU-only,
// replaces ds_swizzle (LDS pipe, ~100cy) on the 16-layer critical chain.
#define DPP_ADD(v, ctrl)                                                        \
    (v) += __int_as_float(__builtin_amdgcn_update_dpp(                          \
               0, __float_as_int(v), (ctrl), 0xF, 0xF, true))

// 16-lane all-reduce sum: xor1, xor2 via quad_perm; then +ror4 (sum of quad
// pairs), +ror8 (all four quads). All lanes end with the row total.
#define REDUCE16(v)                                                             \
    do {                                                                        \
        DPP_ADD(v, 0xB1);   /* quad_perm [1,0,3,2]  */                          \
        DPP_ADD(v, 0x4E);   /* quad_perm [2,3,0,1]  */                          \
        DPP_ADD(v, 0x124);  /* row_ror:4            */                          \
        DPP_ADD(v, 0x128);  /* row_ror:8            */                          \
    } while (0)

// ---------------- k1: fused params + main chain ----------------
// 512 threads = 8 waves; wave handles 4 rows (16 lanes/row, 16 elems/lane).
__global__ __launch_bounds__(512, 6) void k_main(
    const float* __restrict__ z_in, float* __restrict__ z_out,
    const float* __restrict__ pw, const float* __restrict__ pb,
    const float* __restrict__ ps, const float* __restrict__ rz0,
    const float* __restrict__ ra, const float* __restrict__ rb,
    __half* __restrict__ h_ws, float* __restrict__ pbw)
{
    __shared__ float swp[8 * DDIM];
    __shared__ float ssp[8 * DDIM];
    __shared__ float sz0[8 * DDIM];
    __shared__ float sscal[32];   // [0..7]=b, [8..15]=wdots, [16..23]=a, [24..31]=beta

    const int wave = threadIdx.x >> 6;
    const int lane = threadIdx.x & 63;

    // --- prologue: wave p computes layer-pair p's corrected params (sync-free) ---
    {
        const int p = wave;
        const int ip = 2 * p, ir = 2 * p + 1;
        float4 wv  = ((const float4*)(pw  + ip * DDIM))[lane];
        float4 sv  = ((const float4*)(ps  + ip * DDIM))[lane];
        float4 z0v = ((const float4*)(rz0 + ir * DDIM))[lane];
        float m  = wv.x * sv.x + wv.y * sv.y + wv.z * sv.z + wv.w * sv.w;
        float n2 = wv.x * wv.x + wv.y * wv.y + wv.z * wv.z + wv.w * wv.w;
#pragma unroll
        for (int o = 1; o < 64; o <<= 1) {
            m  += __shfl_xor(m,  o, 64);
            n2 += __shfl_xor(n2, o, 64);
        }
        if (m < -1.0f) {                      // wave-uniform branch
            float comp = -1.0f + log1pf(expf(m)) - m;
            float f = comp / sqrtf(n2);
            sv.x += f * wv.x; sv.y += f * wv.y; sv.z += f * wv.z; sv.w += f * wv.w;
        }
        float wd = wv.x * sv.x + wv.y * sv.y + wv.z * sv.z + wv.w * sv.w;
#pragma unroll
        for (int o = 1; o < 64; o <<= 1) wd += __shfl_xor(wd, o, 64);
        // permuted store: element d=lane*4+c -> ((lane&3)<<6)|((lane>>2)<<2)|c
        const int nd = ((lane & 3) << 6) | ((lane >> 2) << 2);
        *((float4*)(swp + p * DDIM + nd)) = wv;
        *((float4*)(ssp + p * DDIM + nd)) = sv;
        *((float4*)(sz0 + p * DDIM + nd)) = z0v;
        if (lane == 0) {
            sscal[p]      = pb[ip];
            sscal[8 + p]  = wd;
            float a = ra[ir], bt = rb[ir];
            if (bt < -a) bt = -a + log1pf(expf(bt));
            sscal[16 + p] = a;
            sscal[24 + p] = bt;
        }
    }
    __syncthreads();

    float pbv[8], wds[8], av[8], bv[8];
#pragma unroll
    for (int p = 0; p < 8; ++p) {
        pbv[p] = uni(sscal[p]);
        wds[p] = uni(sscal[8 + p]);
        av[p]  = uni(sscal[16 + p]);
        bv[p]  = uni(sscal[24 + p]);
    }

    const int g = lane >> 4;      // row-in-wave 0..3
    const int j = lane & 15;      // chunk index in row
    const int row = blockIdx.x * 32 + wave * 4 + g;

    float4 zv[4];
    {
        const float4* zp = (const float4*)(z_in + (size_t)row * DDIM + j * 16);
#pragma unroll
        for (int k = 0; k < 4; ++k) zv[k] = zp[k];
    }

    float r2s[8];
    float pls = 0.0f;
    unsigned hw32[4];

#pragma unroll
    for (int i = 0; i < 16; ++i) {
        if ((i & 1) == 0) {               // planar
            const int p = i >> 1;
            const float4* wb = ((const float4*)swp) + p * 64 + j;
            float t = 0.0f;
#pragma unroll
            for (int k = 0; k < 4; ++k) {
                float4 wv = wb[k * 16];
                t += zv[k].x * wv.x + zv[k].y * wv.y + zv[k].z * wv.z + zv[k].w * wv.w;
            }
            REDUCE16(t);
            float x = t + pbv[p];
            float e = __expf(2.0f * x);
            float act = 1.0f - 2.0f / (e + 1.0f);       // tanh(x)
            const float4* sb = ((const float4*)ssp) + p * 64 + j;
#pragma unroll
            for (int k = 0; k < 4; ++k) {
                float4 sv = sb[k * 16];
                zv[k].x += sv.x * act; zv[k].y += sv.y * act;
                zv[k].z += sv.z * act; zv[k].w += sv.w * act;
            }
            float det = 1.0f + (1.0f - act * act) * wds[p];
            pls += __logf(fabsf(det) + EPSF);
        } else {                           // radial
            const int r = i >> 1;
            const float4* zb = ((const float4*)sz0) + r * 64 + j;
            float4 rd[4];
            float t = 0.0f;
#pragma unroll
            for (int k = 0; k < 4; ++k) {
                float4 zz = zb[k * 16];
                rd[k].x = zv[k].x - zz.x; rd[k].y = zv[k].y - zz.y;
                rd[k].z = zv[k].z - zz.z; rd[k].w = zv[k].w - zz.w;
                t += rd[k].x * rd[k].x + rd[k].y * rd[k].y
                   + rd[k].z * rd[k].z + rd[k].w * rd[k].w;
            }
            REDUCE16(t);
            float rr = sqrtf(t);
            float h = 1.0f / (av[r] + rr);
            float bh = bv[r] * h;
#pragma unroll
            for (int k = 0; k < 4; ++k) {
                zv[k].x += bh * rd[k].x; zv[k].y += bh * rd[k].y;
                zv[k].z += bh * rd[k].z; zv[k].w += bh * rd[k].w;
            }
            r2s[r] = t;
            unsigned hu = (unsigned)__half_as_ushort(__float2half(h));
            if ((r & 1) == 0) hw32[r >> 1] = hu;
            else              hw32[r >> 1] |= hu << 16;
        }
    }

    {
        float4* op = (float4*)(z_out + (size_t)row * DDIM + j * 16);
#pragma unroll
        for (int k = 0; k < 4; ++k) op[k] = zv[k];
        if (j == 0)
            ((uint4*)h_ws)[row] = make_uint4(hw32[0], hw32[1], hw32[2], hw32[3]);
    }

    // per-wave partials: values are row-uniform; combine the 4 row-groups
    const int waveId = blockIdx.x * 8 + wave;
#pragma unroll
    for (int q = 0; q < 9; ++q) {
        float v = (q < 8) ? r2s[q] : pls;
        if (j != 0) v = 0.0f;
        v += __shfl_xor(v, 16, 64);
        v += __shfl_xor(v, 32, 64);
        if (lane == 0) pbw[waveId * 9 + q] = v;
    }
}

// ---------------- k2: reduce wave partials -> R[8], planar loss (9 blocks) ----------------
__global__ __launch_bounds__(1024) void k_stats(
    const float* __restrict__ pbw, double* __restrict__ Rv, double* __restrict__ PL)
{
    __shared__ double sd[1024];
    const int q = blockIdx.x;
    const int t = threadIdx.x;
    double v = 0.0;
    for (int i = t; i < NWAVES; i += 1024) v += (double)pbw[i * 9 + q];
    sd[t] = v;
    __syncthreads();
#pragma unroll
    for (int off = 512; off > 0; off >>= 1) {
        if (t < off) sd[t] += sd[t + off];
        __syncthreads();
    }
    if (t == 0) {
        if (q < 8) Rv[q] = sqrt(sd[0]);
        else       PL[0] = sd[0];
    }
}

// ---------------- k3: radial loss (needs global R) ----------------
__global__ __launch_bounds__(256) void k_rloss(
    const __half* __restrict__ h_ws, const float* __restrict__ ra,
    const float* __restrict__ rb, const double* __restrict__ Rv,
    double* __restrict__ pb_rl)
{
    __shared__ double sd[256];
    __shared__ float sbeta[8], sR[8];
    if (threadIdx.x < 8) {
        int r = threadIdx.x;
        float a = ra[2 * r + 1], bt = rb[2 * r + 1];
        if (bt < -a) bt = -a + log1pf(expf(bt));
        sbeta[r] = bt;
        sR[r] = (float)Rv[r];
    }
    __syncthreads();
    const int row = blockIdx.x * 256 + threadIdx.x;
    uint4 hp = ((const uint4*)h_ws)[row];
    unsigned hw[4] = {hp.x, hp.y, hp.z, hp.w};
    double ls = 0.0;
#pragma unroll
    for (int r = 0; r < 8; ++r) {
        unsigned hu = (hw[r >> 1] >> ((r & 1) * 16)) & 0xFFFFu;
        float h = __half2float(__ushort_as_half((unsigned short)hu));
        float beta = sbeta[r];
        float bh = beta * h;
        float t1 = 1.0f + bh;
        float diag = exp2f(255.0f * __log2f(t1));      // t1^255, t1>0
        float det = diag * (t1 - beta * h * h * sR[r]);
        ls += (double)__logf(fabsf(det) + EPSF);
    }
    sd[threadIdx.x] = ls;
    __syncthreads();
#pragma unroll
    for (int off = 128; off > 0; off >>= 1) {
        if (threadIdx.x < off) sd[threadIdx.x] += sd[threadIdx.x + off];
        __syncthreads();
    }
    if (threadIdx.x == 0) pb_rl[blockIdx.x] = sd[0];
}

// ---------------- k4: final combine ----------------
__global__ __launch_bounds__(256) void k_final(
    const double* __restrict__ pb_rl, const double* __restrict__ PL,
    float* __restrict__ out_loss)
{
    __shared__ double sd[256];
    int t = threadIdx.x;
    double v = 0.0;
    for (int jj = t; jj < NB3; jj += 256) v += pb_rl[jj];
    sd[t] = v;
    __syncthreads();
#pragma unroll
    for (int off = 128; off > 0; off >>= 1) {
        if (t < off) sd[t] += sd[t + off];
        __syncthreads();
    }
    if (t == 0) out_loss[0] = (float)((sd[0] + PL[0]) / (double)B_ROWS);
}

extern "C" void kernel_launch(void* const* d_in, const int* in_sizes, int n_in,
                              void* d_out, int out_size, void* d_ws, size_t ws_size,
                              hipStream_t stream) {
    const float* z   = (const float*)d_in[0];
    const float* pw  = (const float*)d_in[1];
    const float* pb  = (const float*)d_in[2];
    const float* ps  = (const float*)d_in[3];
    const float* rz0 = (const float*)d_in[4];
    const float* ra  = (const float*)d_in[5];
    const float* rb  = (const float*)d_in[6];
    float* out = (float*)d_out;

    char* ws = (char*)d_ws;
    float*  pbw   = (float*)(ws + PBW_OFF);
    double* Rv    = (double*)(ws + RV_OFF);
    double* PL    = (double*)(ws + PL_OFF);
    double* pb_rl = (double*)(ws + PBRL_OFF);
    __half* h_ws  = (__half*)(ws + HW_OFF);

    k_main<<<NB1, 512, 0, stream>>>(z, out, pw, pb, ps, rz0, ra, rb, h_ws, pbw);
    k_stats<<<9, 1024, 0, stream>>>(pbw, Rv, PL);
    k_rloss<<<NB3, 256, 0, stream>>>(h_ws, ra, rb, Rv, pb_rl);
    k_final<<<1, 256, 0, stream>>>(pb_rl, PL, out + (size_t)B_ROWS * DDIM);
}

// Round 7
// 90.958 us; speedup vs baseline: 3.5903x; 1.0809x over previous
//
#include <hip/hip_runtime.h>
#include <hip/hip_fp16.h>
#include <math.h>

#define B_ROWS 131072
#define DDIM 256
#define EPSF 1e-7f
#define NB1 4096            // k_main blocks; 512 thr, 8 waves, 32 rows/block
#define NWAVES (NB1 * 8)    // 32768 per-wave partial slots
#define NB3 512             // k_rloss blocks; NB3*256 == B_ROWS

// ---------- ws layout (bytes) ----------
#define PBW_OFF  0          // float[NWAVES][9] = 1179648
#define RV_OFF   1179648    // double[8]
#define PL_OFF   1179712    // double[1]
#define PBRL_OFF 1179776    // double[NB3] = 4096
#define HW_OFF   1183872    // __half[B_ROWS][8] = 2 MB (end ~3.28 MB)

__device__ __forceinline__ float uni(float x) {   // wave-uniform -> SGPR
    return __int_as_float(__builtin_amdgcn_readfirstlane(__float_as_int(x)));
}

// DPP-based add: v += v permuted by ctrl (within 16-lane DPP rows). VALU-only.
#define DPP_ADD(v, ctrl)                                                        \
    (v) += __int_as_float(__builtin_amdgcn_update_dpp(                          \
               0, __float_as_int(v), (ctrl), 0xF, 0xF, true))

// 16-lane all-reduce sum: xor1, xor2 via quad_perm; then row_ror:4, row_ror:8.
#define REDUCE16(v)                                                             \
    do {                                                                        \
        DPP_ADD(v, 0xB1);   /* quad_perm [1,0,3,2]  */                          \
        DPP_ADD(v, 0x4E);   /* quad_perm [2,3,0,1]  */                          \
        DPP_ADD(v, 0x124);  /* row_ror:4            */                          \
        DPP_ADD(v, 0x128);  /* row_ror:8            */                          \
    } while (0)

// ---------------- k1: fused params + main chain ----------------
// 512 threads = 8 waves; wave handles 4 rows (16 lanes/row, 16 elems/lane).
__global__ __launch_bounds__(512, 6) void k_main(
    const float* __restrict__ z_in, float* __restrict__ z_out,
    const float* __restrict__ pw, const float* __restrict__ pb,
    const float* __restrict__ ps, const float* __restrict__ rz0,
    const float* __restrict__ ra, const float* __restrict__ rb,
    __half* __restrict__ h_ws, float* __restrict__ pbw)
{
    __shared__ float swp[8 * DDIM];
    __shared__ float ssp[8 * DDIM];
    __shared__ float sz0[8 * DDIM];
    __shared__ float sscal[32];   // [0..7]=b, [8..15]=wdots, [16..23]=a, [24..31]=beta

    const int wave = threadIdx.x >> 6;
    const int lane = threadIdx.x & 63;

    // --- prologue: wave p computes layer-pair p's corrected params (sync-free) ---
    {
        const int p = wave;
        const int ip = 2 * p, ir = 2 * p + 1;
        float4 wv  = ((const float4*)(pw  + ip * DDIM))[lane];
        float4 sv  = ((const float4*)(ps  + ip * DDIM))[lane];
        float4 z0v = ((const float4*)(rz0 + ir * DDIM))[lane];
        float m  = wv.x * sv.x + wv.y * sv.y + wv.z * sv.z + wv.w * sv.w;
        float n2 = wv.x * wv.x + wv.y * wv.y + wv.z * wv.z + wv.w * wv.w;
#pragma unroll
        for (int o = 1; o < 64; o <<= 1) {
            m  += __shfl_xor(m,  o, 64);
            n2 += __shfl_xor(n2, o, 64);
        }
        if (m < -1.0f) {                      // wave-uniform branch
            float comp = -1.0f + log1pf(expf(m)) - m;
            float f = comp * __builtin_amdgcn_rsqf(n2);
            sv.x += f * wv.x; sv.y += f * wv.y; sv.z += f * wv.z; sv.w += f * wv.w;
        }
        float wd = wv.x * sv.x + wv.y * sv.y + wv.z * sv.z + wv.w * sv.w;
#pragma unroll
        for (int o = 1; o < 64; o <<= 1) wd += __shfl_xor(wd, o, 64);
        // permuted store: element d=lane*4+c -> ((lane&3)<<6)|((lane>>2)<<2)|c
        const int nd = ((lane & 3) << 6) | ((lane >> 2) << 2);
        *((float4*)(swp + p * DDIM + nd)) = wv;
        *((float4*)(ssp + p * DDIM + nd)) = sv;
        *((float4*)(sz0 + p * DDIM + nd)) = z0v;
        if (lane == 0) {
            sscal[p]      = pb[ip];
            sscal[8 + p]  = wd;
            float a = ra[ir], bt = rb[ir];
            if (bt < -a) bt = -a + log1pf(expf(bt));
            sscal[16 + p] = a;
            sscal[24 + p] = bt;
        }
    }
    __syncthreads();

    float pbv[8], wds[8], av[8], bv[8];
#pragma unroll
    for (int p = 0; p < 8; ++p) {
        pbv[p] = uni(sscal[p]);
        wds[p] = uni(sscal[8 + p]);
        av[p]  = uni(sscal[16 + p]);
        bv[p]  = uni(sscal[24 + p]);
    }

    const int g = lane >> 4;      // row-in-wave 0..3
    const int j = lane & 15;      // chunk index in row
    const int row = blockIdx.x * 32 + wave * 4 + g;

    float4 zv[4];
    {
        const float4* zp = (const float4*)(z_in + (size_t)row * DDIM + j * 16);
#pragma unroll
        for (int k = 0; k < 4; ++k) zv[k] = zp[k];
    }

    float r2s[8];
    float pls = 0.0f;
    unsigned hw32[4];

#pragma unroll
    for (int i = 0; i < 16; ++i) {
        if ((i & 1) == 0) {               // planar
            const int p = i >> 1;
            const float4* wb = ((const float4*)swp) + p * 64 + j;
            // 4 independent partial dot-products (ILP), pairwise combine
            float t0, t1, t2, t3;
            {
                float4 w0 = wb[0], w1 = wb[16], w2 = wb[32], w3 = wb[48];
                t0 = zv[0].x * w0.x + zv[0].y * w0.y + zv[0].z * w0.z + zv[0].w * w0.w;
                t1 = zv[1].x * w1.x + zv[1].y * w1.y + zv[1].z * w1.z + zv[1].w * w1.w;
                t2 = zv[2].x * w2.x + zv[2].y * w2.y + zv[2].z * w2.z + zv[2].w * w2.w;
                t3 = zv[3].x * w3.x + zv[3].y * w3.y + zv[3].z * w3.z + zv[3].w * w3.w;
            }
            float t = (t0 + t1) + (t2 + t3);
            REDUCE16(t);
            float x = t + pbv[p];
            float e = __expf(2.0f * x);
            float act = 1.0f - 2.0f * __builtin_amdgcn_rcpf(e + 1.0f);  // tanh(x)
            const float4* sb = ((const float4*)ssp) + p * 64 + j;
#pragma unroll
            for (int k = 0; k < 4; ++k) {
                float4 sv = sb[k * 16];
                zv[k].x += sv.x * act; zv[k].y += sv.y * act;
                zv[k].z += sv.z * act; zv[k].w += sv.w * act;
            }
            float det = 1.0f + (1.0f - act * act) * wds[p];
            pls += __logf(fabsf(det) + EPSF);
        } else {                           // radial
            const int r = i >> 1;
            const float4* zb = ((const float4*)sz0) + r * 64 + j;
            float4 rd[4];
            float t0, t1, t2, t3;
            {
                float4 z0 = zb[0], z1 = zb[16], z2 = zb[32], z3 = zb[48];
                rd[0].x = zv[0].x - z0.x; rd[0].y = zv[0].y - z0.y;
                rd[0].z = zv[0].z - z0.z; rd[0].w = zv[0].w - z0.w;
                rd[1].x = zv[1].x - z1.x; rd[1].y = zv[1].y - z1.y;
                rd[1].z = zv[1].z - z1.z; rd[1].w = zv[1].w - z1.w;
                rd[2].x = zv[2].x - z2.x; rd[2].y = zv[2].y - z2.y;
                rd[2].z = zv[2].z - z2.z; rd[2].w = zv[2].w - z2.w;
                rd[3].x = zv[3].x - z3.x; rd[3].y = zv[3].y - z3.y;
                rd[3].z = zv[3].z - z3.z; rd[3].w = zv[3].w - z3.w;
                t0 = rd[0].x * rd[0].x + rd[0].y * rd[0].y + rd[0].z * rd[0].z + rd[0].w * rd[0].w;
                t1 = rd[1].x * rd[1].x + rd[1].y * rd[1].y + rd[1].z * rd[1].z + rd[1].w * rd[1].w;
                t2 = rd[2].x * rd[2].x + rd[2].y * rd[2].y + rd[2].z * rd[2].z + rd[2].w * rd[2].w;
                t3 = rd[3].x * rd[3].x + rd[3].y * rd[3].y + rd[3].z * rd[3].z + rd[3].w * rd[3].w;
            }
            float t = (t0 + t1) + (t2 + t3);
            REDUCE16(t);
            float rr = __builtin_amdgcn_sqrtf(t);
            float h = __builtin_amdgcn_rcpf(av[r] + rr);
            float bh = bv[r] * h;
#pragma unroll
            for (int k = 0; k < 4; ++k) {
                zv[k].x += bh * rd[k].x; zv[k].y += bh * rd[k].y;
                zv[k].z += bh * rd[k].z; zv[k].w += bh * rd[k].w;
            }
            r2s[r] = t;
            unsigned hu = (unsigned)__half_as_ushort(__float2half(h));
            if ((r & 1) == 0) hw32[r >> 1] = hu;
            else              hw32[r >> 1] |= hu << 16;
        }
    }

    {
        float4* op = (float4*)(z_out + (size_t)row * DDIM + j * 16);
#pragma unroll
        for (int k = 0; k < 4; ++k) op[k] = zv[k];
        if (j == 0)
            ((uint4*)h_ws)[row] = make_uint4(hw32[0], hw32[1], hw32[2], hw32[3]);
    }

    // per-wave partials: values are row-uniform; combine the 4 row-groups
    const int waveId = blockIdx.x * 8 + wave;
#pragma unroll
    for (int q = 0; q < 9; ++q) {
        float v = (q < 8) ? r2s[q] : pls;
        if (j != 0) v = 0.0f;
        v += __shfl_xor(v, 16, 64);
        v += __shfl_xor(v, 32, 64);
        if (lane == 0) pbw[waveId * 9 + q] = v;
    }
}

// ---------------- k2: reduce wave partials -> R[8], planar loss (9 blocks) ----------------
__global__ __launch_bounds__(1024) void k_stats(
    const float* __restrict__ pbw, double* __restrict__ Rv, double* __restrict__ PL)
{
    __shared__ double sd[1024];
    const int q = blockIdx.x;
    const int t = threadIdx.x;
    double v = 0.0;
    for (int i = t; i < NWAVES; i += 1024) v += (double)pbw[i * 9 + q];
    sd[t] = v;
    __syncthreads();
#pragma unroll
    for (int off = 512; off > 0; off >>= 1) {
        if (t < off) sd[t] += sd[t + off];
        __syncthreads();
    }
    if (t == 0) {
        if (q < 8) Rv[q] = sqrt(sd[0]);
        else       PL[0] = sd[0];
    }
}

// ---------------- k3: radial loss (needs global R) ----------------
__global__ __launch_bounds__(256) void k_rloss(
    const __half* __restrict__ h_ws, const float* __restrict__ ra,
    const float* __restrict__ rb, const double* __restrict__ Rv,
    double* __restrict__ pb_rl)
{
    __shared__ double sd[256];
    __shared__ float sbeta[8], sR[8];
    if (threadIdx.x < 8) {
        int r = threadIdx.x;
        float a = ra[2 * r + 1], bt = rb[2 * r + 1];
        if (bt < -a) bt = -a + log1pf(expf(bt));
        sbeta[r] = bt;
        sR[r] = (float)Rv[r];
    }
    __syncthreads();
    const int row = blockIdx.x * 256 + threadIdx.x;
    uint4 hp = ((const uint4*)h_ws)[row];
    unsigned hw[4] = {hp.x, hp.y, hp.z, hp.w};
    double ls = 0.0;
#pragma unroll
    for (int r = 0; r < 8; ++r) {
        unsigned hu = (hw[r >> 1] >> ((r & 1) * 16)) & 0xFFFFu;
        float h = __half2float(__ushort_as_half((unsigned short)hu));
        float beta = sbeta[r];
        float bh = beta * h;
        float t1 = 1.0f + bh;
        float diag = exp2f(255.0f * __log2f(t1));      // t1^255, t1>0
        float det = diag * (t1 - beta * h * h * sR[r]);
        ls += (double)__logf(fabsf(det) + EPSF);
    }
    sd[threadIdx.x] = ls;
    __syncthreads();
#pragma unroll
    for (int off = 128; off > 0; off >>= 1) {
        if (threadIdx.x < off) sd[threadIdx.x] += sd[threadIdx.x + off];
        __syncthreads();
    }
    if (threadIdx.x == 0) pb_rl[blockIdx.x] = sd[0];
}

// ---------------- k4: final combine ----------------
__global__ __launch_bounds__(256) void k_final(
    const double* __restrict__ pb_rl, const double* __restrict__ PL,
    float* __restrict__ out_loss)
{
    __shared__ double sd[256];
    int t = threadIdx.x;
    double v = 0.0;
    for (int jj = t; jj < NB3; jj += 256) v += pb_rl[jj];
    sd[t] = v;
    __syncthreads();
#pragma unroll
    for (int off = 128; off > 0; off >>= 1) {
        if (t < off) sd[t] += sd[t + off];
        __syncthreads();
    }
    if (t == 0) out_loss[0] = (float)((sd[0] + PL[0]) / (double)B_ROWS);
}

extern "C" void kernel_launch(void* const* d_in, const int* in_sizes, int n_in,
                              void* d_out, int out_size, void* d_ws, size_t ws_size,
                              hipStream_t stream) {
    const float* z   = (const float*)d_in[0];
    const float* pw  = (const float*)d_in[1];
    const float* pb  = (const float*)d_in[2];
    const float* ps  = (const float*)d_in[3];
    const float* rz0 = (const float*)d_in[4];
    const float* ra  = (const float*)d_in[5];
    const float* rb  = (const float*)d_in[6];
    float* out = (float*)d_out;

    char* ws = (char*)d_ws;
    float*  pbw   = (float*)(ws + PBW_OFF);
    double* Rv    = (double*)(ws + RV_OFF);
    double* PL    = (double*)(ws + PL_OFF);
    double* pb_rl = (double*)(ws + PBRL_OFF);
    __half* h_ws  = (__half*)(ws + HW_OFF);

    k_main<<<NB1, 512, 0, stream>>>(z, out, pw, pb, ps, rz0, ra, rb, h_ws, pbw);
    k_stats<<<9, 1024, 0, stream>>>(pbw, Rv, PL);
    k_rloss<<<NB3, 256, 0, stream>>>(h_ws, ra, rb, Rv, pb_rl);
    k_final<<<1, 256, 0, stream>>>(pb_rl, PL, out + (size_t)B_ROWS * DDIM);
}